// Round 8
// baseline (86.165 us; speedup 1.0000x reference)
//
#include <hip/hip_runtime.h>
#include <stdint.h>

// ---------------- problem constants ----------------
#define B_ROWS 16384
#define NF 26
#define NV 100000
#define ND 13
#define NH 400
#define ZPAD 416     // GEMM K padded (13 tiles of 32)
#define EPS 1e-5f

typedef __attribute__((ext_vector_type(8))) short short8;
typedef __attribute__((ext_vector_type(4))) float f32x4;
typedef __attribute__((ext_vector_type(4))) unsigned int uint4v;

__device__ inline float bf2f(unsigned short u) {
    union { unsigned int i; float f; } v; v.i = (unsigned int)u << 16; return v.f;
}
__device__ inline unsigned short f2bf(float f) {
    union { float f; unsigned int i; } v; v.f = f;
    unsigned int r = (v.i + 0x7fff + ((v.i >> 16) & 1)) >> 16;
    return (unsigned short)r;
}

// direct global->LDS DMA, 16B/lane; lds dest = wave-uniform base + lane*16
typedef __attribute__((address_space(1))) const unsigned int g_u32;
typedef __attribute__((address_space(3))) unsigned int l_u32;
__device__ __forceinline__ void gload_lds16(const void* g, void* l) {
    __builtin_amdgcn_global_load_lds((g_u32*)g, (l_u32*)l, 16, 0, 0);
}

// ---------------- ws layout (bytes) ----------------
// Xf  : bf16 [27][16384][16] = 14,155,776  (planes 0..25 emb, 26 dense)
// Z1  : bf16 [16384][416]    = 13,631,488
// Z2  : bf16 [16384][416]    = 13,631,488
// W1s : staged [14][4][448][8] = 401,408
// W2s : staged [13][4][448][8] = 372,736
// base: f32 [16384] ; st: f32 gsum1,gsq1,gsum2,gsq2 (416 each)
#define XF_OFF   0
#define Z1_OFF   14155776
#define Z2_OFF   27787264
#define W1S_OFF  41418752
#define W2S_OFF  41820160
#define BASE_OFF 42192896
#define ST_OFF   42258432

// =====================================================================
// prep: blocks 0..94  -> W1/W2 staged bf16 [NT][4][448][8]; block0 zeros st
//       blocks 95..126-> base[r]=bd ; dense plane Xf[26][r][0..15]
// =====================================================================
__global__ __launch_bounds__(512) void prep_w(
    const float* __restrict__ W1, const float* __restrict__ W2,
    const float* __restrict__ Xd, const float* __restrict__ bd,
    unsigned short* __restrict__ W1s, unsigned short* __restrict__ W2s,
    unsigned short* __restrict__ Xf, float* __restrict__ base,
    float* __restrict__ st)
{
    int bid = blockIdx.x, tid = threadIdx.x;
    if (bid >= 95) {
        int r = (bid - 95) * 512 + tid;          // 0..16383 exact
        base[r] = bd[0];
        unsigned short o[16];
        #pragma unroll
        for (int j = 0; j < 16; ++j) {
            float v = (j < ND) ? Xd[(size_t)r * ND + j] : 0.f;
            o[j] = f2bf(v);
        }
        uint4v* dst = (uint4v*)(Xf + ((size_t)26 * B_ROWS + r) * 16);
        dst[0] = *(uint4v*)&o[0];
        dst[1] = *(uint4v*)&o[8];
        return;
    }
    if (bid == 0) {
        for (int i = tid; i < 1664; i += 512) st[i] = 0.f;
    }
    int c = bid * 512 + tid;
    if (c >= 48384) return;
    const float* W; unsigned short* dst; int K; int cc;
    if (c < 25088) { W = W1; dst = W1s; K = 429; cc = c; }
    else           { W = W2; dst = W2s; K = 400; cc = c - 25088; }
    int n  = cc % 448;
    int q  = (cc / 448) & 3;
    int kt = cc / 1792;
    unsigned short o[8];
    #pragma unroll
    for (int j = 0; j < 8; ++j) {
        int k = kt * 32 + q * 8 + j;
        float v = (n < NH && k < K) ? W[(size_t)k * NH + n] : 0.f;
        o[j] = f2bf(v);
    }
    *(uint4v*)(dst + (size_t)cc * 8) = *(uint4v*)o;
}

// =====================================================================
// gather_fields: grid 1664 x 256, XCD-pinned by field (xcd = bid & 7).
// XCD x owns fields {x, x+8, x+16, x+24(<26)} -> its fm1 slice (<=1.6MB)
// stays L2-resident. Each block: one field, a contiguous row chunk.
//   Xf[f][r][0..15] = bf16(emb[f][idx]);  base[r] += fm1[f][idx] (atomic)
// =====================================================================
__global__ __launch_bounds__(256) void gather_fields(
    const int* __restrict__ Xcat, const float* __restrict__ fm1,
    const float* __restrict__ emb, unsigned short* __restrict__ Xf,
    float* __restrict__ base)
{
    const int x = blockIdx.x & 7;
    const int s = blockIdx.x >> 3;           // 0..207
    const int nf = (x < 2) ? 4 : 3;
    const int nc = 208 / nf;                 // 52 or 69
    const int fi = s / nc;
    if (fi >= nf) return;
    const int f = x + 8 * fi;
    const int chunk = s - fi * nc;
    const int rpc = (B_ROWS + nc - 1) / nc;  // 316 or 238
    const int r0 = chunk * rpc;
    int r1 = r0 + rpc; if (r1 > B_ROWS) r1 = B_ROWS;

    const float* et = emb + (size_t)f * NV * 16;
    const float* ft = fm1 + (size_t)f * NV;
    unsigned short* xp = Xf + (size_t)f * B_ROWS * 16;

    for (int r = r0 + threadIdx.x; r < r1; r += 256) {
        int idx = Xcat[(size_t)r * NF + f];
        const float* p = et + (size_t)idx * 16;
        f32x4 a = *(const f32x4*)p;
        f32x4 b = *(const f32x4*)(p + 4);
        f32x4 c = *(const f32x4*)(p + 8);
        f32x4 d = *(const f32x4*)(p + 12);
        float fv = ft[idx];
        unsigned short o[16];
        #pragma unroll
        for (int j = 0; j < 4; ++j) {
            o[j]      = f2bf(a[j]);
            o[j + 4]  = f2bf(b[j]);
            o[j + 8]  = f2bf(c[j]);
            o[j + 12] = f2bf(d[j]);
        }
        uint4v* dst = (uint4v*)(xp + (size_t)r * 16);
        dst[0] = *(uint4v*)&o[0];
        dst[1] = *(uint4v*)&o[8];
        atomicAdd(&base[r], fv);
    }
}

// =====================================================================
// gemm1: Z1 = [emb|dense] @ W1 + b1 from field-major Xf, fused FM terms.
// Structure = proven mfma_gemm2: per-tile af prefetch (coalesced 16B/lane
// from Xf planes), W dbuf via gload_lds, 1 barrier/tile. FM 2nd-order +
// dense-dot accumulated from the same fragments (nhalf==0 waves).
// grid 256 x 512, 2 blocks/CU.
// =====================================================================
__global__ __launch_bounds__(512, 2) void gemm1_xf(
    const unsigned short* __restrict__ Xf,
    const unsigned short* __restrict__ Wst,
    const float* __restrict__ bias, const float* __restrict__ Wd,
    unsigned short* __restrict__ Z, float* __restrict__ base,
    float* __restrict__ gsum, float* __restrict__ gsq)
{
    __shared__ unsigned short b_s[2][14336];      // 57,344 B
    __shared__ float sredS[4][416];               // 6,656 B
    __shared__ float sredQ[4][416];               // 6,656 B

    const int tid = threadIdx.x;
    const int lane = tid & 63;
    const int wv = tid >> 6;
    const int rowgrp = wv & 3;
    const int nhalf = wv >> 2;
    const int l15 = lane & 15;
    const int qh = lane >> 4;
    const int m0 = blockIdx.x * 64;
    const int arow = m0 + rowgrp * 16 + l15;
    const int c0 = nhalf * 208;
    const int NFRAG = nhalf ? 12 : 13;
    const int fpar = qh >> 1;
    const int khalf = (qh & 1) << 3;

    auto stage = [&](int kt, int buf) {
        #pragma unroll
        for (int i = 0; i < 4; ++i) {
            int cchunk = wv * 256 + i * 64 + lane;
            gload_lds16(Wst + (size_t)kt * 14336 + (size_t)cchunk * 8,
                        &b_s[buf][(size_t)(wv * 256 + i * 64) * 8]);
        }
    };
    auto ld_af = [&](int kt) -> short8 {
        if (kt < 13) {
            int f = 2 * kt + fpar;
            return *(const short8*)(Xf + ((size_t)f * B_ROWS + arow) * 16 + khalf);
        }
        short8 z;
        #pragma unroll
        for (int j = 0; j < 8; ++j) z[j] = 0;
        if (qh < 2)
            z = *(const short8*)(Xf + ((size_t)26 * B_ROWS + arow) * 16 + khalf);
        return z;
    };

    float wd[8];
    #pragma unroll
    for (int j = 0; j < 8; ++j) {
        int cd = khalf + j;
        wd[j] = (cd < ND) ? Wd[cd] : 0.f;
    }

    f32x4 acc[13];
    #pragma unroll
    for (int i = 0; i < 13; ++i) acc[i] = f32x4{0.f, 0.f, 0.f, 0.f};
    float s8[8] = {0.f,0.f,0.f,0.f,0.f,0.f,0.f,0.f};
    float ssacc = 0.f, dsum = 0.f;

    if (wv < 7) stage(0, 0);
    short8 af_next = ld_af(0);
    __syncthreads();

    #pragma unroll
    for (int kt = 0; kt < 14; ++kt) {
        if (kt + 1 < 14 && wv < 7) stage(kt + 1, (kt + 1) & 1);
        short8 af = af_next;
        if (kt + 1 < 14) af_next = ld_af(kt + 1);
        if (nhalf == 0) {
            if (kt < 13) {
                #pragma unroll
                for (int j = 0; j < 8; ++j) {
                    float v = bf2f((unsigned short)af[j]);
                    s8[j] += v; ssacc += v * v;
                }
            } else if (qh < 2) {
                #pragma unroll
                for (int j = 0; j < 8; ++j)
                    dsum += bf2f((unsigned short)af[j]) * wd[j];
            }
        }
        const unsigned short* bb = &b_s[kt & 1][(size_t)(qh * 448 + c0 + l15) * 8];
        #pragma unroll
        for (int nn = 0; nn < 13; ++nn) {
            if (nn < NFRAG) {
                short8 bf = *(const short8*)(bb + nn * 128);
                acc[nn] = __builtin_amdgcn_mfma_f32_16x16x32_bf16(af, bf, acc[nn], 0, 0, 0);
            }
        }
        __syncthreads();
    }

    // ---- FM base: ix = sum_k s_k^2 - sum v^2 ; cross-qh reduce (verified R6) ----
    if (nhalf == 0) {
        float red = 0.f;
        #pragma unroll
        for (int j = 0; j < 8; ++j) {
            float sf = s8[j] + __shfl_xor(s8[j], 32, 64);
            red += sf * sf;
        }
        red -= (ssacc + __shfl_xor(ssacc, 32, 64));
        red += __shfl_xor(red, 16, 64);
        float dr = dsum + __shfl_xor(dsum, 16, 64);
        dr += __shfl_xor(dr, 32, 64);
        if (qh == 0) base[arow] = base[arow] + 0.5f * red + dr;
    }

    // ---- epilogue: +bias, bf16 store, fp32 column stats ----
    #pragma unroll
    for (int nn = 0; nn < 13; ++nn) {
        if (nn < NFRAG) {
            int col = c0 + nn * 16 + l15;
            float bv = bias[col];
            float ps = 0.f, pq = 0.f;
            #pragma unroll
            for (int q = 0; q < 4; ++q) {
                float val = acc[nn][q] + bv;
                ps += val; pq += val * val;
                Z[(size_t)(m0 + rowgrp * 16 + qh * 4 + q) * ZPAD + col] = f2bf(val);
            }
            ps += __shfl_xor(ps, 16, 64); ps += __shfl_xor(ps, 32, 64);
            pq += __shfl_xor(pq, 16, 64); pq += __shfl_xor(pq, 32, 64);
            if (lane < 16) { sredS[rowgrp][col] = ps; sredQ[rowgrp][col] = pq; }
        }
    }
    if (nhalf == 1) {   // zero-pad cols 400..415 for GEMM2's A reads
        int col = NH + l15;
        #pragma unroll
        for (int q = 0; q < 4; ++q)
            Z[(size_t)(m0 + rowgrp * 16 + qh * 4 + q) * ZPAD + col] = 0;
    }
    __syncthreads();
    for (int c = tid; c < NH; c += 512) {
        float s = sredS[0][c] + sredS[1][c] + sredS[2][c] + sredS[3][c];
        float q = sredQ[0][c] + sredQ[1][c] + sredQ[2][c] + sredQ[3][c];
        atomicAdd(&gsum[c], s);
        atomicAdd(&gsq[c], q);
    }
}

// =====================================================================
// K2: MFMA GEMM with fused BN1+ReLU on A, 2-phase gload_lds W staging.
// =====================================================================
__global__ __launch_bounds__(512, 2) void mfma_gemm2(
    const unsigned short* __restrict__ A,
    const unsigned short* __restrict__ Wst,
    const float* __restrict__ bias,
    const float* __restrict__ gsumIn, const float* __restrict__ gsqIn,
    const float* __restrict__ g, const float* __restrict__ be,
    unsigned short* __restrict__ Z,
    float* __restrict__ gsum, float* __restrict__ gsq)
{
    __shared__ unsigned short b_s[2][14336];
    __shared__ float sredS[4][416];
    __shared__ float sredQ[4][416];
    __shared__ float alpha_s[416], beta_s[416];

    const int tid = threadIdx.x;
    const int lane = tid & 63;
    const int wv = tid >> 6;
    const int rowgrp = wv & 3;
    const int nhalf = wv >> 2;
    const int l15 = lane & 15;
    const int qh = lane >> 4;
    const int m0 = blockIdx.x * 64;
    const int arow = m0 + rowgrp * 16 + l15;
    const int c0 = nhalf * 208;
    const int NFRAG = nhalf ? 12 : 13;

    for (int c = tid; c < ZPAD; c += 512) {
        float a = 0.f, b = 0.f;
        if (c < NH) {
            float mean = gsumIn[c] * (1.f / B_ROWS);
            float var  = gsqIn[c] * (1.f / B_ROWS) - mean * mean;
            a = g[c] * rsqrtf(var + EPS);
            b = be[c] - mean * a;
        }
        alpha_s[c] = a; beta_s[c] = b;
    }

    f32x4 acc[13];
    #pragma unroll
    for (int i = 0; i < 13; ++i) acc[i] = f32x4{0.f, 0.f, 0.f, 0.f};

    auto stage = [&](int kt, int buf) {
        #pragma unroll
        for (int i = 0; i < 4; ++i) {
            int cchunk = wv * 256 + i * 64 + lane;
            gload_lds16(Wst + (size_t)kt * 14336 + (size_t)cchunk * 8,
                        &b_s[buf][(size_t)(wv * 256 + i * 64) * 8]);
        }
    };

    if (wv < 7) stage(0, 0);
    short8 af_next = *(const short8*)(A + (size_t)arow * ZPAD + qh * 8);
    __syncthreads();

    for (int kt = 0; kt < 13; ++kt) {
        if (kt + 1 < 13 && wv < 7) stage(kt + 1, (kt + 1) & 1);
        short8 af = af_next;
        if (kt + 1 < 13)
            af_next = *(const short8*)(A + (size_t)arow * ZPAD + (kt + 1) * 32 + qh * 8);
        int k0 = kt * 32 + qh * 8;
        #pragma unroll
        for (int j = 0; j < 8; ++j) {
            float f = bf2f((unsigned short)af[j]);
            f = fmaxf(0.f, alpha_s[k0 + j] * f + beta_s[k0 + j]);
            af[j] = (short)f2bf(f);
        }
        const unsigned short* bb = &b_s[kt & 1][(size_t)(qh * 448 + c0 + l15) * 8];
        #pragma unroll
        for (int nn = 0; nn < 13; ++nn) {
            if (nn < NFRAG) {
                short8 bf = *(const short8*)(bb + nn * 128);
                acc[nn] = __builtin_amdgcn_mfma_f32_16x16x32_bf16(af, bf, acc[nn], 0, 0, 0);
            }
        }
        __syncthreads();
    }

    #pragma unroll
    for (int nn = 0; nn < 13; ++nn) {
        if (nn < NFRAG) {
            int col = c0 + nn * 16 + l15;
            float bv = bias[col];
            float ps = 0.f, pq = 0.f;
            #pragma unroll
            for (int q = 0; q < 4; ++q) {
                float v = acc[nn][q] + bv;
                ps += v; pq += v * v;
                Z[(size_t)(m0 + rowgrp * 16 + qh * 4 + q) * ZPAD + col] = f2bf(v);
            }
            ps += __shfl_xor(ps, 16, 64); ps += __shfl_xor(ps, 32, 64);
            pq += __shfl_xor(pq, 16, 64); pq += __shfl_xor(pq, 32, 64);
            if (lane < 16) { sredS[rowgrp][col] = ps; sredQ[rowgrp][col] = pq; }
        }
    }
    __syncthreads();
    for (int c = tid; c < NH; c += 512) {
        float s = sredS[0][c] + sredS[1][c] + sredS[2][c] + sredS[3][c];
        float q = sredQ[0][c] + sredQ[1][c] + sredQ[2][c] + sredQ[3][c];
        atomicAdd(&gsum[c], s);
        atomicAdd(&gsq[c], q);
    }
}

// =====================================================================
// final: finalize BN2 in-block, then out[r] = base[r] + relu(.)·W3 + b3
// =====================================================================
__global__ __launch_bounds__(256) void final_kernel(
    const unsigned short* __restrict__ Z2,
    const float* __restrict__ gsum2, const float* __restrict__ gsq2,
    const float* __restrict__ g2, const float* __restrict__ be2,
    const float* __restrict__ W3, const float* __restrict__ b3,
    const float* __restrict__ base, float* __restrict__ out)
{
    __shared__ float a2s[NH], b2s[NH], w3s[NH];
    int tid = threadIdx.x;
    for (int c = tid; c < NH; c += 256) {
        float mean = gsum2[c] * (1.f / B_ROWS);
        float var  = gsq2[c] * (1.f / B_ROWS) - mean * mean;
        float a = g2[c] * rsqrtf(var + EPS);
        a2s[c] = a;
        b2s[c] = be2[c] - mean * a;
        w3s[c] = W3[c];
    }
    __syncthreads();
    int lane = tid & 63;
    int wv = tid >> 6;
    bool act = lane < 50;
    int cb = lane * 8;
    float al[8], bb[8], w3[8];
    #pragma unroll
    for (int j = 0; j < 8; ++j) {
        al[j] = act ? a2s[cb + j] : 0.f;
        bb[j] = act ? b2s[cb + j] : 0.f;
        w3[j] = act ? w3s[cb + j] : 0.f;
    }
    int r0 = blockIdx.x * 32 + wv * 8;
    float bias3 = b3[0];
    for (int t = 0; t < 8; t += 2) {
        int r = r0 + t;
        float acc0 = 0.f, acc1 = 0.f;
        if (act) {
            short8 z0 = *(const short8*)(Z2 + (size_t)r * ZPAD + cb);
            short8 z1 = *(const short8*)(Z2 + (size_t)(r + 1) * ZPAD + cb);
            #pragma unroll
            for (int j = 0; j < 8; ++j) {
                acc0 += fmaxf(0.f, al[j] * bf2f((unsigned short)z0[j]) + bb[j]) * w3[j];
                acc1 += fmaxf(0.f, al[j] * bf2f((unsigned short)z1[j]) + bb[j]) * w3[j];
            }
        }
        #pragma unroll
        for (int off = 32; off; off >>= 1) {
            acc0 += __shfl_xor(acc0, off, 64);
            acc1 += __shfl_xor(acc1, off, 64);
        }
        if (lane == 0) out[r] = base[r] + acc0 + bias3;
        if (lane == 1) out[r + 1] = base[r + 1] + acc1 + bias3;
    }
}

// =====================================================================
extern "C" void kernel_launch(void* const* d_in, const int* in_sizes, int n_in,
                              void* d_out, int out_size, void* d_ws, size_t ws_size,
                              hipStream_t stream)
{
    const int*   Xcat = (const int*)d_in[0];
    const float* Xd   = (const float*)d_in[1];
    const float* fm1  = (const float*)d_in[2];
    const float* emb  = (const float*)d_in[3];
    const float* Wd   = (const float*)d_in[4];
    const float* bd   = (const float*)d_in[5];
    const float* W1   = (const float*)d_in[6];
    const float* b1   = (const float*)d_in[7];
    const float* g1   = (const float*)d_in[8];
    const float* be1  = (const float*)d_in[9];
    const float* W2   = (const float*)d_in[10];
    const float* b2   = (const float*)d_in[11];
    const float* g2   = (const float*)d_in[12];
    const float* be2  = (const float*)d_in[13];
    const float* W3   = (const float*)d_in[14];
    const float* b3   = (const float*)d_in[15];

    char* ws = (char*)d_ws;
    unsigned short* Xf  = (unsigned short*)(ws + XF_OFF);
    unsigned short* Z1  = (unsigned short*)(ws + Z1_OFF);
    unsigned short* Z2  = (unsigned short*)(ws + Z2_OFF);
    unsigned short* W1s = (unsigned short*)(ws + W1S_OFF);
    unsigned short* W2s = (unsigned short*)(ws + W2S_OFF);
    float* base = (float*)(ws + BASE_OFF);
    float* st   = (float*)(ws + ST_OFF);
    float* gsum1 = st;          float* gsq1 = st + 416;
    float* gsum2 = st + 832;    float* gsq2 = st + 1248;
    float* out = (float*)d_out;

    // 1: stage W1/W2, zero stats, base=bd, dense plane
    prep_w<<<127, 512, 0, stream>>>(W1, W2, Xd, bd, W1s, W2s, Xf, base, st);

    // 2: field-partitioned gather (XCD-pinned fm1), base += fm1 terms
    gather_fields<<<1664, 256, 0, stream>>>(Xcat, fm1, emb, Xf, base);

    // 3: Z1 = X @ W1 + b1 from Xf planes, FM terms -> base, stats1
    gemm1_xf<<<256, 512, 0, stream>>>(Xf, W1s, b1, Wd, Z1, base, gsum1, gsq1);

    // 4: Z2 = relu(bn1(Z1)) @ W2 + b2, stats2
    mfma_gemm2<<<256, 512, 0, stream>>>(Z1, W2s, b2, gsum1, gsq1, g1, be1,
                                        Z2, gsum2, gsq2);

    // 5: out = base + relu(bn2(Z2))·W3 + b3
    final_kernel<<<512, 256, 0, stream>>>(Z2, gsum2, gsq2, g2, be2, W3, b3, base, out);
}